// Round 5
// baseline (74.075 us; speedup 1.0000x reference)
//
#include <hip/hip_runtime.h>
#include <math.h>

typedef float f32x16 __attribute__((ext_vector_type(16)));
typedef __bf16 bf16x8 __attribute__((ext_vector_type(8)));

constexpr int DEG = 64;
constexpr int KC  = 32;
constexpr int D   = 64;
constexpr float EPS = 1.1920929e-05f;  // 100 * f32 eps

// chunk-major bf16 LDS layout: 16B chunk c (8 bf16) of row r lives at
// ushort index c*512 + ((r^c)*8). Fragment reads (row varies over 32 lanes,
// chunk fixed per half) are lane-linear permuted 512B segments -> conflict-free.
// global_load_lds writes lane i at c*512 + i*8, so lane i must fetch row i^c.
__device__ __forceinline__ int yidx(int row, int chunk) {
    return (chunk << 9) + ((row ^ chunk) << 3);
}

// ---------------- prep: x(f32) -> xhi/xlo(bf16) + row norms ----------------
__global__ __launch_bounds__(256)
void rgc_prep(const float* __restrict__ x,
              unsigned short* __restrict__ xhi,
              unsigned short* __restrict__ xlo,
              float* __restrict__ xnrm, int nrows) {
    const int id  = blockIdx.x * 256 + threadIdx.x;  // row-chunk task
    const int row = id >> 3;
    const int c   = id & 7;
    if (row >= nrows) return;
    const float* src = x + ((size_t)row << 6) + (c << 3);
    const float4 v0 = *reinterpret_cast<const float4*>(src);
    const float4 v1 = *reinterpret_cast<const float4*>(src + 4);
    const float fv[8] = {v0.x, v0.y, v0.z, v0.w, v1.x, v1.y, v1.z, v1.w};
    bf16x8 h, e;
    float s = 0.f;
    #pragma unroll
    for (int j = 0; j < 8; ++j) {
        const float f = fv[j];
        s += f * f;
        const __bf16 hb = (__bf16)f;   // RNE
        h[j] = hb;
        e[j] = (__bf16)(f - (float)hb);
    }
    s += __shfl_xor(s, 1); s += __shfl_xor(s, 2); s += __shfl_xor(s, 4);
    if (c == 0) xnrm[row] = s;
    const size_t o = ((size_t)row << 6) + (c << 3);
    *reinterpret_cast<bf16x8*>(xhi + o) = h;
    *reinterpret_cast<bf16x8*>(xlo + o) = e;
}

// ---------------- main ----------------
__global__ __launch_bounds__(128, 4)
void rgc_main(const unsigned short* __restrict__ xhi,
              const unsigned short* __restrict__ xlo,
              const float* __restrict__ xnrm,
              const int*   __restrict__ nbr,
              float*       __restrict__ out) {
    __shared__ __align__(16) unsigned short yhi[4096];  // 8 KB
    __shared__ __align__(16) unsigned short ylo[4096];  // 8 KB
    __shared__ float nrm[64];
    __shared__ float wsh[KC];
    __shared__ float pdist[64];
    __shared__ float obuf[64];

    const int n = blockIdx.x;
    const int t = threadIdx.x;
    const int w = t >> 6;    // wave id = m-tile id
    const int l = t & 63;

    const int my = nbr[(n << 6) + l];
    if (w == 0) nrm[l] = xnrm[my];

    // stage: wave0 -> yhi, wave1 -> ylo; 8 chunks x 64 lanes x 16B
    const unsigned short* xsrc = w ? xlo : xhi;
    unsigned short*       ydst = w ? ylo : yhi;
    #pragma unroll
    for (int c = 0; c < 8; ++c) {
        const int g = __shfl_xor(my, c);   // row that belongs at lane slot
        const unsigned short* src = xsrc + ((size_t)g << 6) + (c << 3);
        __builtin_amdgcn_global_load_lds(
            (const __attribute__((address_space(1))) unsigned int*)src,
            (__attribute__((address_space(3))) unsigned int*)(ydst + (c << 9)),
            16, 0, 0);
    }
    asm volatile("s_waitcnt vmcnt(0)" ::: "memory");
    __syncthreads();

    // ---- fragments: D = Xm · Xk^T (k = lane dim, m = reg dim) ----
    const int frow = l & 31;
    const int kh   = l >> 5;
    bf16x8 amh[4], aml[4], bkh[4], bkl[4];
    #pragma unroll
    for (int s = 0; s < 4; ++s) {
        const int c  = 2 * s + kh;
        const int kb = yidx(frow, c);
        bkh[s] = *reinterpret_cast<bf16x8*>(&yhi[kb]);
        bkl[s] = *reinterpret_cast<bf16x8*>(&ylo[kb]);
    }
    if (w == 0) {   // Gram symmetry
        #pragma unroll
        for (int s = 0; s < 4; ++s) { amh[s] = bkh[s]; aml[s] = bkl[s]; }
    } else {
        #pragma unroll
        for (int s = 0; s < 4; ++s) {
            const int c  = 2 * s + kh;
            const int mb = yidx(32 + frow, c);
            amh[s] = *reinterpret_cast<bf16x8*>(&yhi[mb]);
            aml[s] = *reinterpret_cast<bf16x8*>(&ylo[mb]);
        }
    }

    f32x16 acc = {};
    #pragma unroll
    for (int s = 0; s < 4; ++s)
        acc = __builtin_amdgcn_mfma_f32_32x32x16_bf16(amh[s], bkh[s], acc, 0, 0, 0);
    #pragma unroll
    for (int s = 0; s < 4; ++s)
        acc = __builtin_amdgcn_mfma_f32_32x32x16_bf16(amh[s], bkl[s], acc, 0, 0, 0);
    #pragma unroll
    for (int s = 0; s < 4; ++s)
        acc = __builtin_amdgcn_mfma_f32_32x32x16_bf16(aml[s], bkh[s], acc, 0, 0, 0);

    // ---- sq -> l2 -> dist partial (reduce over m in registers) ----
    const float nk  = nrm[l & 31];
    const int   mb0 = w * 32 + 4 * kh;
    float4 nm4[4];
    #pragma unroll
    for (int q = 0; q < 4; ++q)
        nm4[q] = *reinterpret_cast<const float4*>(&nrm[mb0 + 8 * q]);

    float s = 0.f;
    #pragma unroll
    for (int r = 0; r < 16; ++r) {
        const float nm = ((const float*)&nm4[r >> 2])[r & 3];
        const float sq = __builtin_fmaf(-2.0f, acc[r], nm + nk);
        s += __builtin_amdgcn_sqrtf(__builtin_fabsf(sq) + EPS);
    }
    s += __shfl_xor(s, 32);
    if (l < 32) pdist[w * 32 + l] = s;
    __syncthreads();

    // ---- softmax over 32 candidates (both waves, lane-parallel) ----
    const int k = l & 31;
    const float d = pdist[k] + pdist[32 + k];
    float dmin = d;
    #pragma unroll
    for (int m = 1; m <= 16; m <<= 1) dmin = fminf(dmin, __shfl_xor(dmin, m));
    const float ez = __expf(dmin - d);
    float Z = ez;
    #pragma unroll
    for (int m = 1; m <= 16; m <<= 1) Z += __shfl_xor(Z, m);
    if (t < 32) wsh[k] = ez * (64.0f / Z);   // row_sum = DEG
    __syncthreads();

    // ---- output: out[n][l] = sum_k w[k]*Y[k][l]; wave w does k in [16w,16w+16) ----
    const int oc = l >> 3;
    const int ow = l & 7;
    float o = 0.f;
    #pragma unroll
    for (int kk = 0; kk < 16; ++kk) {
        const int kx = w * 16 + kk;
        const int bi = yidx(kx, oc) + ow;
        const float f = __uint_as_float((unsigned)yhi[bi] << 16)
                      + __uint_as_float((unsigned)ylo[bi] << 16);
        o += wsh[kx] * f;
    }
    if (w == 1) obuf[l] = o;
    __syncthreads();
    if (w == 0) out[(size_t)n * D + l] = o + obuf[l];
}

// ---------------- fallback (R4 path, no workspace needed) ----------------
__global__ __launch_bounds__(128, 4)
void rgc_fallback(const float* __restrict__ x,
                  const int*   __restrict__ nbr,
                  float*       __restrict__ out) {
    __shared__ __align__(16) unsigned short yhi[4096];
    __shared__ __align__(16) unsigned short ylo[4096];
    __shared__ float nrm[64];
    __shared__ float wsh[KC];
    __shared__ float pdist[64];
    __shared__ float obuf[64];

    const int n = blockIdx.x;
    const int t = threadIdx.x;
    const int w = t >> 6;
    const int l = t & 63;

    const int srow = t >> 3;
    const int sc   = t & 7;
    int gidx[4];
    #pragma unroll
    for (int it = 0; it < 4; ++it)
        gidx[it] = nbr[(n << 6) + it * 16 + srow];

    #pragma unroll
    for (int it = 0; it < 4; ++it) {
        const int row = it * 16 + srow;
        const float* src = x + ((size_t)gidx[it] << 6) + (sc << 3);
        const float4 v0 = *reinterpret_cast<const float4*>(src);
        const float4 v1 = *reinterpret_cast<const float4*>(src + 4);
        const float fv[8] = {v0.x, v0.y, v0.z, v0.w, v1.x, v1.y, v1.z, v1.w};
        float s = 0.f;
        bf16x8 h, e;
        #pragma unroll
        for (int j = 0; j < 8; ++j) {
            const float f = fv[j];
            s += f * f;
            const __bf16 hb = (__bf16)f;
            h[j] = hb;
            e[j] = (__bf16)(f - (float)hb);
        }
        s += __shfl_xor(s, 1); s += __shfl_xor(s, 2); s += __shfl_xor(s, 4);
        if (sc == 0) nrm[row] = s;
        const int base = yidx(row, sc);
        *reinterpret_cast<bf16x8*>(&yhi[base]) = h;
        *reinterpret_cast<bf16x8*>(&ylo[base]) = e;
    }
    __syncthreads();

    const int frow = l & 31;
    const int kh   = l >> 5;
    bf16x8 amh[4], aml[4], bkh[4], bkl[4];
    #pragma unroll
    for (int s = 0; s < 4; ++s) {
        const int c  = 2 * s + kh;
        const int kb = yidx(frow, c);
        bkh[s] = *reinterpret_cast<bf16x8*>(&yhi[kb]);
        bkl[s] = *reinterpret_cast<bf16x8*>(&ylo[kb]);
    }
    if (w == 0) {
        #pragma unroll
        for (int s = 0; s < 4; ++s) { amh[s] = bkh[s]; aml[s] = bkl[s]; }
    } else {
        #pragma unroll
        for (int s = 0; s < 4; ++s) {
            const int c  = 2 * s + kh;
            const int mb = yidx(32 + frow, c);
            amh[s] = *reinterpret_cast<bf16x8*>(&yhi[mb]);
            aml[s] = *reinterpret_cast<bf16x8*>(&ylo[mb]);
        }
    }

    f32x16 acc = {};
    #pragma unroll
    for (int s = 0; s < 4; ++s)
        acc = __builtin_amdgcn_mfma_f32_32x32x16_bf16(amh[s], bkh[s], acc, 0, 0, 0);
    #pragma unroll
    for (int s = 0; s < 4; ++s)
        acc = __builtin_amdgcn_mfma_f32_32x32x16_bf16(amh[s], bkl[s], acc, 0, 0, 0);
    #pragma unroll
    for (int s = 0; s < 4; ++s)
        acc = __builtin_amdgcn_mfma_f32_32x32x16_bf16(aml[s], bkh[s], acc, 0, 0, 0);

    const float nk  = nrm[l & 31];
    const int   mb0 = w * 32 + 4 * kh;
    float4 nm4[4];
    #pragma unroll
    for (int q = 0; q < 4; ++q)
        nm4[q] = *reinterpret_cast<const float4*>(&nrm[mb0 + 8 * q]);

    float s = 0.f;
    #pragma unroll
    for (int r = 0; r < 16; ++r) {
        const float nm = ((const float*)&nm4[r >> 2])[r & 3];
        const float sq = __builtin_fmaf(-2.0f, acc[r], nm + nk);
        s += __builtin_amdgcn_sqrtf(__builtin_fabsf(sq) + EPS);
    }
    s += __shfl_xor(s, 32);
    if (l < 32) pdist[w * 32 + l] = s;
    __syncthreads();

    const int k = l & 31;
    const float d = pdist[k] + pdist[32 + k];
    float dmin = d;
    #pragma unroll
    for (int m = 1; m <= 16; m <<= 1) dmin = fminf(dmin, __shfl_xor(dmin, m));
    const float ez = __expf(dmin - d);
    float Z = ez;
    #pragma unroll
    for (int m = 1; m <= 16; m <<= 1) Z += __shfl_xor(Z, m);
    if (t < 32) wsh[k] = ez * (64.0f / Z);
    __syncthreads();

    const int oc = l >> 3;
    const int ow = l & 7;
    float o = 0.f;
    #pragma unroll
    for (int kk = 0; kk < 16; ++kk) {
        const int kx = w * 16 + kk;
        const int bi = yidx(kx, oc) + ow;
        const float f = __uint_as_float((unsigned)yhi[bi] << 16)
                      + __uint_as_float((unsigned)ylo[bi] << 16);
        o += wsh[kx] * f;
    }
    if (w == 1) obuf[l] = o;
    __syncthreads();
    if (w == 0) out[(size_t)n * D + l] = o + obuf[l];
}

extern "C" void kernel_launch(void* const* d_in, const int* in_sizes, int n_in,
                              void* d_out, int out_size, void* d_ws, size_t ws_size,
                              hipStream_t stream) {
    const float* x   = (const float*)d_in[0];
    const int*   nbr = (const int*)d_in[1];
    float*       out = (float*)d_out;
    const int n_nodes = in_sizes[0] / D;   // 20000
    const size_t need = (size_t)n_nodes * D * 2 * sizeof(unsigned short)
                      + (size_t)n_nodes * sizeof(float);
    if (d_ws != nullptr && ws_size >= need) {
        unsigned short* xhi  = (unsigned short*)d_ws;
        unsigned short* xlo  = xhi + (size_t)n_nodes * D;
        float*          xnrm = (float*)(xlo + (size_t)n_nodes * D);
        const int tasks = n_nodes * 8;
        rgc_prep<<<(tasks + 255) / 256, 256, 0, stream>>>(x, xhi, xlo, xnrm, n_nodes);
        rgc_main<<<n_nodes, 128, 0, stream>>>(xhi, xlo, xnrm, nbr, out);
    } else {
        rgc_fallback<<<n_nodes, 128, 0, stream>>>(x, nbr, out);
    }
}